// Round 2
// baseline (431.644 us; speedup 1.0000x reference)
//
#include <hip/hip_runtime.h>

// Problem constants (fixed by the reference setup_inputs).
constexpr int kB = 4, kT = 4096, kN = 4, kC = 1024;
constexpr int kChunks = kC / 4;                      // float4 chunks per (b,t,n) row = 256
constexpr int kThreads = kB * kT * kChunks;          // 4,194,304 threads, one per (b,t,c4)

__global__ __launch_bounds__(256) void hyperconn_kernel(
    const float4* __restrict__ x4,
    const float* __restrict__ pre_w,     // (n,)
    const float* __restrict__ post_w,    // (n,)
    const float* __restrict__ res_w,     // (n,n) row-major, res_w[m*kN+n]
    float4* __restrict__ out4)
{
    // ---- softmax of the tiny weight vectors, fp32, wave-uniform ----
    float pw[kN], qw[kN], rw[kN][kN];
    float pmax = -1e30f, qmax = -1e30f;
#pragma unroll
    for (int i = 0; i < kN; ++i) {
        pw[i] = pre_w[i];
        qw[i] = post_w[i];
        pmax = fmaxf(pmax, pw[i]);
        qmax = fmaxf(qmax, qw[i]);
    }
    float ps = 0.f, qs = 0.f;
#pragma unroll
    for (int i = 0; i < kN; ++i) {
        pw[i] = __expf(pw[i] - pmax); ps += pw[i];
        qw[i] = __expf(qw[i] - qmax); qs += qw[i];
    }
    const float pinv = 1.f / ps, qinv = 1.f / qs;
#pragma unroll
    for (int i = 0; i < kN; ++i) { pw[i] *= pinv; qw[i] *= qinv; }
#pragma unroll
    for (int m = 0; m < kN; ++m)
#pragma unroll
        for (int n = 0; n < kN; ++n)
            rw[m][n] = res_w[m * kN + n];

    // ---- per-thread position: (bt, c4) ----
    const int tid = blockIdx.x * blockDim.x + threadIdx.x;    // < 2^22
    const int c4  = tid & (kChunks - 1);
    const int bt  = tid >> 8;                                  // kChunks = 256
    const int idx0 = bt * (kN * kChunks) + c4;                 // float4 index of (bt, n=0, c4)

    // 4 coalesced 16B loads, one per n-plane (stride C floats = 256 float4)
    float4 xv[kN];
#pragma unroll
    for (int n = 0; n < kN; ++n) xv[n] = x4[idx0 + n * kChunks];

    float xf[kN][4];
#pragma unroll
    for (int n = 0; n < kN; ++n) {
        xf[n][0] = xv[n].x; xf[n][1] = xv[n].y;
        xf[n][2] = xv[n].z; xf[n][3] = xv[n].w;
    }

    // h[j] = sum_n pw[n] * x[n][j]
    float h[4];
#pragma unroll
    for (int j = 0; j < 4; ++j) {
        float s = xf[0][j] * pw[0];
#pragma unroll
        for (int n = 1; n < kN; ++n) s = fmaf(xf[n][j], pw[n], s);
        h[j] = s;
    }

    // out[m][j] = qw[m]*h[j] + sum_n rw[m][n]*x[n][j]
#pragma unroll
    for (int m = 0; m < kN; ++m) {
        float o[4];
#pragma unroll
        for (int j = 0; j < 4; ++j) {
            float s = h[j] * qw[m];
#pragma unroll
            for (int n = 0; n < kN; ++n) s = fmaf(xf[n][j], rw[m][n], s);
            o[j] = s;
        }
        float4 ov;
        ov.x = o[0]; ov.y = o[1]; ov.z = o[2]; ov.w = o[3];
        out4[idx0 + m * kChunks] = ov;
    }
}

extern "C" void kernel_launch(void* const* d_in, const int* in_sizes, int n_in,
                              void* d_out, int out_size, void* d_ws, size_t ws_size,
                              hipStream_t stream) {
    const float4* x4 = (const float4*)d_in[0];
    const float* pre_w  = (const float*)d_in[1];
    const float* post_w = (const float*)d_in[2];
    const float* res_w  = (const float*)d_in[3];
    float4* out4 = (float4*)d_out;

    const int block = 256;
    const int grid = kThreads / block;   // 16384 blocks
    hipLaunchKernelGGL(hyperconn_kernel, dim3(grid), dim3(block), 0, stream,
                       x4, pre_w, post_w, res_w, out4);
}